// Round 1
// baseline (238.208 us; speedup 1.0000x reference)
//
#include <hip/hip_runtime.h>
#include <limits.h>

#define NBATCH 2
#define DIM 128
#define NVOX 131072
#define NQ 131072
#define NC 128
#define OCC_SIZE (NBATCH * DIM * DIM * DIM)   // 4,194,304 ints = 16 MB

// d_out float layout (concatenated reference outputs)
#define QF_OFF  0
#define IDX_OFF (NQ * NC)                 // 16,777,216
#define WV_OFF  (IDX_OFF + NQ * 8)        // 17,825,792
#define ACC_OFF (WV_OFF + NQ * 8)         // 18,874,368

// ---------------- init: occ = -1, shift = INT_MAX, accum = 0 ----------------
__global__ void k_init(int* __restrict__ occ, int* __restrict__ shift,
                       float* __restrict__ accum) {
    int tid = blockIdx.x * blockDim.x + threadIdx.x;
    int stride = gridDim.x * blockDim.x;
    if (tid < 6) shift[tid] = INT_MAX;
    for (int j = tid; j < NVOX; j += stride) accum[j] = 0.f;
    for (int j = tid; j < OCC_SIZE; j += stride) occ[j] = -1;
}

// ---------------- per-batch component-wise min (wave-reduced) ----------------
__global__ void k_shift(const int* __restrict__ coords, int* __restrict__ shift) {
    int i = blockIdx.x * blockDim.x + threadIdx.x;
    int m0 = INT_MAX, m1 = INT_MAX, m2 = INT_MAX;  // batch 0 x,y,z
    int m3 = INT_MAX, m4 = INT_MAX, m5 = INT_MAX;  // batch 1 x,y,z
    if (i < NVOX) {
        int4 c = ((const int4*)coords)[i];
        if (c.x == 0) { m0 = c.y; m1 = c.z; m2 = c.w; }
        else          { m3 = c.y; m4 = c.z; m5 = c.w; }
    }
#define WREDUCE(mv)                                           \
    _Pragma("unroll")                                         \
    for (int off = 32; off >= 1; off >>= 1)                   \
        mv = min(mv, __shfl_xor(mv, off, 64));
    WREDUCE(m0) WREDUCE(m1) WREDUCE(m2)
    WREDUCE(m3) WREDUCE(m4) WREDUCE(m5)
#undef WREDUCE
    if ((threadIdx.x & 63) == 0) {
        atomicMin(&shift[0], m0); atomicMin(&shift[1], m1); atomicMin(&shift[2], m2);
        atomicMin(&shift[3], m3); atomicMin(&shift[4], m4); atomicMin(&shift[5], m5);
    }
}

// ---------------- build occupancy: last-write-wins == atomicMax -------------
__global__ void k_build(const int* __restrict__ coords, const int* __restrict__ shift,
                        int* __restrict__ occ) {
    int i = blockIdx.x * blockDim.x + threadIdx.x;
    if (i >= NVOX) return;
    int4 c = ((const int4*)coords)[i];
    int b = c.x;
    int x = c.y - shift[b * 3 + 0];
    int y = c.z - shift[b * 3 + 1];
    int z = c.w - shift[b * 3 + 2];
    atomicMax(&occ[((b * DIM + x) * DIM + y) * DIM + z], i);
}

// ---------------- main: one wave per query, lane = 2 channels ---------------
__global__ __launch_bounds__(256) void k_query(
    const float* __restrict__ qpts, const float* __restrict__ feats,
    const int* __restrict__ occ, const int* __restrict__ shift,
    float* __restrict__ out) {
    int gtid = blockIdx.x * blockDim.x + threadIdx.x;
    int q = gtid >> 6;
    int lane = threadIdx.x & 63;
    if (q >= NQ) return;

    float4 qp = ((const float4*)qpts)[q];
    int qb = (int)qp.x;
    float qx = qp.y - (float)shift[qb * 3 + 0];
    float qy = qp.z - (float)shift[qb * 3 + 1];
    float qz = qp.w - (float)shift[qb * 3 + 2];
    float fx0 = floorf(qx), fy0 = floorf(qy), fz0 = floorf(qz);
    float fx = qx - fx0, fy = qy - fy0, fz = qz - fz0;
    int ix = (int)fx0, iy = (int)fy0, iz = (int)fz0;

    const float2* f2 = (const float2*)feats;
    float* out_idx = out + IDX_OFF + (size_t)q * 8;
    float* out_wv  = out + WV_OFF  + (size_t)q * 8;
    float* accum   = out + ACC_OFF;

    float acc0 = 0.f, acc1 = 0.f, wsum = 0.f;
#pragma unroll
    for (int k = 0; k < 8; ++k) {
        const int ox = (k >> 2) & 1, oy = (k >> 1) & 1, oz = k & 1;
        int cx = ix + ox, cy = iy + oy, cz = iz + oz;
        bool inb = ((unsigned)cx < DIM) && ((unsigned)cy < DIM) && ((unsigned)cz < DIM);
        int ccx = min(max(cx, 0), DIM - 1);
        int ccy = min(max(cy, 0), DIM - 1);
        int ccz = min(max(cz, 0), DIM - 1);
        int idx = occ[((qb * DIM + ccx) * DIM + ccy) * DIM + ccz];
        float w = (ox ? fx : 1.f - fx) * (oy ? fy : 1.f - fy) * (oz ? fz : 1.f - fz);
        bool valid = inb && (idx >= 0);
        float wvk = valid ? w : 0.f;
        wsum += wvk;
        if (valid) {  // wave-uniform branch: all lanes share the scalar predicate
            float2 fv = f2[(size_t)idx * 64 + lane];
            acc0 = fmaf(wvk, fv.x, acc0);
            acc1 = fmaf(wvk, fv.y, acc1);
        }
        if (lane == k) {
            out_idx[k] = valid ? (float)idx : -1.f;
            out_wv[k]  = wvk;
            if (valid && wvk != 0.f) atomicAdd(&accum[idx], wvk);
        }
    }
    float denom = fmaxf(wsum, 1e-8f);
    float2 r;
    r.x = acc0 / denom;
    r.y = acc1 / denom;
    ((float2*)(out + QF_OFF))[(size_t)q * 64 + lane] = r;
}

extern "C" void kernel_launch(void* const* d_in, const int* in_sizes, int n_in,
                              void* d_out, int out_size, void* d_ws, size_t ws_size,
                              hipStream_t stream) {
    const int*   coords = (const int*)d_in[0];
    const float* feats  = (const float*)d_in[1];
    const float* qpts   = (const float*)d_in[2];
    float* out = (float*)d_out;

    // workspace layout: [0..5] shift ints (256B-aligned pad), then occ grid
    int* shift = (int*)d_ws;
    int* occ   = (int*)((char*)d_ws + 256);

    k_init<<<2048, 256, 0, stream>>>(occ, shift, out + ACC_OFF);
    k_shift<<<(NVOX + 255) / 256, 256, 0, stream>>>(coords, shift);
    k_build<<<(NVOX + 255) / 256, 256, 0, stream>>>(coords, shift, occ);
    k_query<<<(NQ * 64 + 255) / 256, 256, 0, stream>>>(qpts, feats, occ, shift, out);
}

// Round 2
// 102.918 us; speedup vs baseline: 2.3145x; 2.3145x over previous
//
#include <hip/hip_runtime.h>
#include <limits.h>

#define NBATCH 2
#define DIM 128
#define NVOX 131072
#define NQ 131072
#define NC 128
#define OCC_SIZE (NBATCH * DIM * DIM * DIM)   // 4,194,304 ints = 16 MB

// d_out float layout (concatenated reference outputs)
#define QF_OFF  0
#define IDX_OFF (NQ * NC)                 // 16,777,216
#define WV_OFF  (IDX_OFF + NQ * 8)        // 17,825,792
#define ACC_OFF (WV_OFF + NQ * 8)         // 18,874,368

// ---------------- init: occ = -1, shift = INT_MAX, accum = 0 ----------------
__global__ void k_init(int* __restrict__ occ, int* __restrict__ shift,
                       float* __restrict__ accum) {
    int tid = blockIdx.x * blockDim.x + threadIdx.x;
    int stride = gridDim.x * blockDim.x;
    if (tid < 6) shift[tid] = INT_MAX;
    for (int j = tid; j < NVOX; j += stride) accum[j] = 0.f;
    int4* occ4 = (int4*)occ;
    int4 neg1 = make_int4(-1, -1, -1, -1);
    for (int j = tid; j < OCC_SIZE / 4; j += stride) occ4[j] = neg1;
}

// ------- per-batch component-wise min: wave reduce -> LDS -> 1 atomic/block --
#define SHIFT_BLOCKS 64
__global__ __launch_bounds__(256) void k_shift(const int* __restrict__ coords,
                                               int* __restrict__ shift) {
    __shared__ int sm[4][6];   // [wave][component]
    int tid = blockIdx.x * blockDim.x + threadIdx.x;
    int stride = gridDim.x * blockDim.x;       // 16384
    int m0 = INT_MAX, m1 = INT_MAX, m2 = INT_MAX;
    int m3 = INT_MAX, m4 = INT_MAX, m5 = INT_MAX;
    const int4* c4 = (const int4*)coords;
    for (int i = tid; i < NVOX; i += stride) {
        int4 c = c4[i];
        if (c.x == 0) { m0 = min(m0, c.y); m1 = min(m1, c.z); m2 = min(m2, c.w); }
        else          { m3 = min(m3, c.y); m4 = min(m4, c.z); m5 = min(m5, c.w); }
    }
#define WREDUCE(mv)                                           \
    _Pragma("unroll")                                         \
    for (int off = 32; off >= 1; off >>= 1)                   \
        mv = min(mv, __shfl_xor(mv, off, 64));
    WREDUCE(m0) WREDUCE(m1) WREDUCE(m2)
    WREDUCE(m3) WREDUCE(m4) WREDUCE(m5)
#undef WREDUCE
    int wave = threadIdx.x >> 6;
    if ((threadIdx.x & 63) == 0) {
        sm[wave][0] = m0; sm[wave][1] = m1; sm[wave][2] = m2;
        sm[wave][3] = m3; sm[wave][4] = m4; sm[wave][5] = m5;
    }
    __syncthreads();
    if (threadIdx.x == 0) {
        m0 = min(min(sm[0][0], sm[1][0]), min(sm[2][0], sm[3][0]));
        m1 = min(min(sm[0][1], sm[1][1]), min(sm[2][1], sm[3][1]));
        m2 = min(min(sm[0][2], sm[1][2]), min(sm[2][2], sm[3][2]));
        m3 = min(min(sm[0][3], sm[1][3]), min(sm[2][3], sm[3][3]));
        m4 = min(min(sm[0][4], sm[1][4]), min(sm[2][4], sm[3][4]));
        m5 = min(min(sm[0][5], sm[1][5]), min(sm[2][5], sm[3][5]));
        atomicMin(&shift[0], m0); atomicMin(&shift[1], m1); atomicMin(&shift[2], m2);
        atomicMin(&shift[3], m3); atomicMin(&shift[4], m4); atomicMin(&shift[5], m5);
    }
}

// ---------------- build occupancy: last-write-wins == atomicMax -------------
__global__ void k_build(const int* __restrict__ coords, const int* __restrict__ shift,
                        int* __restrict__ occ) {
    int i = blockIdx.x * blockDim.x + threadIdx.x;
    if (i >= NVOX) return;
    int4 c = ((const int4*)coords)[i];
    int b = c.x;
    int x = c.y - shift[b * 3 + 0];
    int y = c.z - shift[b * 3 + 1];
    int z = c.w - shift[b * 3 + 2];
    atomicMax(&occ[((b * DIM + x) * DIM + y) * DIM + z], i);
}

// ---------------- main: one wave per query, lane = 2 channels ---------------
__global__ __launch_bounds__(256) void k_query(
    const float* __restrict__ qpts, const float* __restrict__ feats,
    const int* __restrict__ occ, const int* __restrict__ shift,
    float* __restrict__ out) {
    int gtid = blockIdx.x * blockDim.x + threadIdx.x;
    int q = gtid >> 6;
    int lane = threadIdx.x & 63;
    if (q >= NQ) return;

    float4 qp = ((const float4*)qpts)[q];
    int qb = (int)qp.x;
    float qx = qp.y - (float)shift[qb * 3 + 0];
    float qy = qp.z - (float)shift[qb * 3 + 1];
    float qz = qp.w - (float)shift[qb * 3 + 2];
    float fx0 = floorf(qx), fy0 = floorf(qy), fz0 = floorf(qz);
    float fx = qx - fx0, fy = qy - fy0, fz = qz - fz0;
    int ix = (int)fx0, iy = (int)fy0, iz = (int)fz0;

    const float2* f2 = (const float2*)feats;
    float* out_idx = out + IDX_OFF + (size_t)q * 8;
    float* out_wv  = out + WV_OFF  + (size_t)q * 8;
    float* accum   = out + ACC_OFF;

    float acc0 = 0.f, acc1 = 0.f, wsum = 0.f;
#pragma unroll
    for (int k = 0; k < 8; ++k) {
        const int ox = (k >> 2) & 1, oy = (k >> 1) & 1, oz = k & 1;
        int cx = ix + ox, cy = iy + oy, cz = iz + oz;
        bool inb = ((unsigned)cx < DIM) && ((unsigned)cy < DIM) && ((unsigned)cz < DIM);
        int ccx = min(max(cx, 0), DIM - 1);
        int ccy = min(max(cy, 0), DIM - 1);
        int ccz = min(max(cz, 0), DIM - 1);
        int idx = occ[((qb * DIM + ccx) * DIM + ccy) * DIM + ccz];
        float w = (ox ? fx : 1.f - fx) * (oy ? fy : 1.f - fy) * (oz ? fz : 1.f - fz);
        bool valid = inb && (idx >= 0);
        float wvk = valid ? w : 0.f;
        wsum += wvk;
        if (valid) {  // wave-uniform branch: all lanes share the scalar predicate
            float2 fv = f2[(size_t)idx * 64 + lane];
            acc0 = fmaf(wvk, fv.x, acc0);
            acc1 = fmaf(wvk, fv.y, acc1);
        }
        if (lane == k) {
            out_idx[k] = valid ? (float)idx : -1.f;
            out_wv[k]  = wvk;
            if (valid && wvk != 0.f) atomicAdd(&accum[idx], wvk);
        }
    }
    float denom = fmaxf(wsum, 1e-8f);
    float2 r;
    r.x = acc0 / denom;
    r.y = acc1 / denom;
    ((float2*)(out + QF_OFF))[(size_t)q * 64 + lane] = r;
}

extern "C" void kernel_launch(void* const* d_in, const int* in_sizes, int n_in,
                              void* d_out, int out_size, void* d_ws, size_t ws_size,
                              hipStream_t stream) {
    const int*   coords = (const int*)d_in[0];
    const float* feats  = (const float*)d_in[1];
    const float* qpts   = (const float*)d_in[2];
    float* out = (float*)d_out;

    // workspace layout: [0..5] shift ints (256B-aligned pad), then occ grid
    int* shift = (int*)d_ws;
    int* occ   = (int*)((char*)d_ws + 256);

    k_init<<<2048, 256, 0, stream>>>(occ, shift, out + ACC_OFF);
    k_shift<<<SHIFT_BLOCKS, 256, 0, stream>>>(coords, shift);
    k_build<<<(NVOX + 255) / 256, 256, 0, stream>>>(coords, shift, occ);
    k_query<<<(NQ * 64 + 255) / 256, 256, 0, stream>>>(qpts, feats, occ, shift, out);
}

// Round 3
// 51.016 us; speedup vs baseline: 4.6693x; 2.0174x over previous
//
#include <hip/hip_runtime.h>
#include <limits.h>

#define NBATCH 2
#define DIM 128
#define NVOX 131072
#define NQ 131072
#define NC 128
#define OCC_SIZE (NBATCH * DIM * DIM * DIM)   // 4,194,304 ints = 16 MB

// d_out float layout (concatenated reference outputs)
#define QF_OFF  0
#define IDX_OFF (NQ * NC)                 // 16,777,216
#define WV_OFF  (IDX_OFF + NQ * 8)        // 17,825,792
#define ACC_OFF (WV_OFF + NQ * 8)         // 18,874,368

// ---------------- init: occ = -1, shift = INT_MAX, accum = 0 ----------------
__global__ void k_init(int* __restrict__ occ, int* __restrict__ shift,
                       float* __restrict__ accum) {
    int tid = blockIdx.x * blockDim.x + threadIdx.x;
    int stride = gridDim.x * blockDim.x;
    if (tid < 6) shift[tid] = INT_MAX;
    for (int j = tid; j < NVOX; j += stride) accum[j] = 0.f;
    int4* occ4 = (int4*)occ;
    int4 neg1 = make_int4(-1, -1, -1, -1);
    for (int j = tid; j < OCC_SIZE / 4; j += stride) occ4[j] = neg1;
}

// ------- per-batch component-wise min: wave reduce -> LDS -> 1 atomic/block --
#define SHIFT_BLOCKS 64
__global__ __launch_bounds__(256) void k_shift(const int* __restrict__ coords,
                                               int* __restrict__ shift) {
    __shared__ int sm[4][6];   // [wave][component]
    int tid = blockIdx.x * blockDim.x + threadIdx.x;
    int stride = gridDim.x * blockDim.x;
    int m0 = INT_MAX, m1 = INT_MAX, m2 = INT_MAX;
    int m3 = INT_MAX, m4 = INT_MAX, m5 = INT_MAX;
    const int4* c4 = (const int4*)coords;
    for (int i = tid; i < NVOX; i += stride) {
        int4 c = c4[i];
        if (c.x == 0) { m0 = min(m0, c.y); m1 = min(m1, c.z); m2 = min(m2, c.w); }
        else          { m3 = min(m3, c.y); m4 = min(m4, c.z); m5 = min(m5, c.w); }
    }
#define WREDUCE(mv)                                           \
    _Pragma("unroll")                                         \
    for (int off = 32; off >= 1; off >>= 1)                   \
        mv = min(mv, __shfl_xor(mv, off, 64));
    WREDUCE(m0) WREDUCE(m1) WREDUCE(m2)
    WREDUCE(m3) WREDUCE(m4) WREDUCE(m5)
#undef WREDUCE
    int wave = threadIdx.x >> 6;
    if ((threadIdx.x & 63) == 0) {
        sm[wave][0] = m0; sm[wave][1] = m1; sm[wave][2] = m2;
        sm[wave][3] = m3; sm[wave][4] = m4; sm[wave][5] = m5;
    }
    __syncthreads();
    if (threadIdx.x == 0) {
        m0 = min(min(sm[0][0], sm[1][0]), min(sm[2][0], sm[3][0]));
        m1 = min(min(sm[0][1], sm[1][1]), min(sm[2][1], sm[3][1]));
        m2 = min(min(sm[0][2], sm[1][2]), min(sm[2][2], sm[3][2]));
        m3 = min(min(sm[0][3], sm[1][3]), min(sm[2][3], sm[3][3]));
        m4 = min(min(sm[0][4], sm[1][4]), min(sm[2][4], sm[3][4]));
        m5 = min(min(sm[0][5], sm[1][5]), min(sm[2][5], sm[3][5]));
        atomicMin(&shift[0], m0); atomicMin(&shift[1], m1); atomicMin(&shift[2], m2);
        atomicMin(&shift[3], m3); atomicMin(&shift[4], m4); atomicMin(&shift[5], m5);
    }
}

// ---------------- build occupancy: last-write-wins == atomicMax -------------
__global__ void k_build(const int* __restrict__ coords, const int* __restrict__ shift,
                        int* __restrict__ occ) {
    int i = blockIdx.x * blockDim.x + threadIdx.x;
    if (i >= NVOX) return;
    int4 c = ((const int4*)coords)[i];
    int b = c.x;
    int x = c.y - shift[b * 3 + 0];
    int y = c.z - shift[b * 3 + 1];
    int z = c.w - shift[b * 3 + 2];
    atomicMax(&occ[((b * DIM + x) * DIM + y) * DIM + z], i);
}

// -------- main: 8 queries per wave. Scalar phase: lane=(qi,corner k). -------
// -------- Gather phase: ballot-compacted, lane=channel pair.          -------
__global__ __launch_bounds__(256) void k_query(
    const float* __restrict__ qpts, const float* __restrict__ feats,
    const int* __restrict__ occ, const int* __restrict__ shift,
    float* __restrict__ out) {
    int lane = threadIdx.x & 63;
    int gwave = blockIdx.x * 4 + (threadIdx.x >> 6);
    int qbase = gwave * 8;                     // 8 queries per wave

    // ---- scalar phase: this lane handles corner k of query qbase+qi ----
    int qi = lane >> 3, k = lane & 7;
    int q = qbase + qi;
    float4 qp = ((const float4*)qpts)[q];
    int qb = (int)qp.x;
    float qx = qp.y - (float)shift[qb * 3 + 0];
    float qy = qp.z - (float)shift[qb * 3 + 1];
    float qz = qp.w - (float)shift[qb * 3 + 2];
    float fx0 = floorf(qx), fy0 = floorf(qy), fz0 = floorf(qz);
    float fx = qx - fx0, fy = qy - fy0, fz = qz - fz0;
    int ox = (k >> 2) & 1, oy = (k >> 1) & 1, oz = k & 1;
    int cx = (int)fx0 + ox, cy = (int)fy0 + oy, cz = (int)fz0 + oz;
    bool inb = ((unsigned)cx < DIM) && ((unsigned)cy < DIM) && ((unsigned)cz < DIM);
    int ccx = min(max(cx, 0), DIM - 1);
    int ccy = min(max(cy, 0), DIM - 1);
    int ccz = min(max(cz, 0), DIM - 1);
    int idx = occ[((qb * DIM + ccx) * DIM + ccy) * DIM + ccz];
    float w = (ox ? fx : 1.f - fx) * (oy ? fy : 1.f - fy) * (oz ? fz : 1.f - fz);
    bool valid = inb && (idx >= 0);
    float wvk = valid ? w : 0.f;

    // coalesced side outputs: q*8+k == qbase*8 + lane
    out[IDX_OFF + (size_t)qbase * 8 + lane] = valid ? (float)idx : -1.f;
    out[WV_OFF  + (size_t)qbase * 8 + lane] = wvk;
    if (valid && wvk != 0.f) atomicAdd(out + ACC_OFF + idx, wvk);

    // per-query wsum: reduce within each 8-lane group
    float wsum = wvk;
    wsum += __shfl_xor(wsum, 1, 64);
    wsum += __shfl_xor(wsum, 2, 64);
    wsum += __shfl_xor(wsum, 4, 64);

    // ---- gather phase: lane = channel pair; only valid corners touched ----
    int sidx = valid ? idx : 0;
    unsigned long long vm = __ballot(wvk != 0.f);
    const float2* f2 = (const float2*)feats;
    float2 acc[8];
#pragma unroll
    for (int g = 0; g < 8; ++g) { acc[g].x = 0.f; acc[g].y = 0.f; }
#pragma unroll
    for (int g = 0; g < 8; ++g) {
        unsigned int sub = (unsigned int)(vm >> (g * 8)) & 0xffu;
        while (sub) {                          // wave-uniform loop
            int j = __ffs(sub) - 1; sub &= sub - 1;
            int src = g * 8 + j;
            float wv_j = __shfl(wvk, src, 64);
            int   idx_j = __shfl(sidx, src, 64);
            float2 fv = f2[(size_t)idx_j * 64 + lane];
            acc[g].x = fmaf(wv_j, fv.x, acc[g].x);
            acc[g].y = fmaf(wv_j, fv.y, acc[g].y);
        }
    }

    // ---- epilogue: 8 coalesced float2 stores ----
    float2* qf = (float2*)(out + QF_OFF);
#pragma unroll
    for (int g = 0; g < 8; ++g) {
        float ws = __shfl(wsum, g * 8, 64);
        float denom = fmaxf(ws, 1e-8f);
        float2 r;
        r.x = acc[g].x / denom;
        r.y = acc[g].y / denom;
        qf[(size_t)(qbase + g) * 64 + lane] = r;
    }
}

extern "C" void kernel_launch(void* const* d_in, const int* in_sizes, int n_in,
                              void* d_out, int out_size, void* d_ws, size_t ws_size,
                              hipStream_t stream) {
    const int*   coords = (const int*)d_in[0];
    const float* feats  = (const float*)d_in[1];
    const float* qpts   = (const float*)d_in[2];
    float* out = (float*)d_out;

    int* shift = (int*)d_ws;
    int* occ   = (int*)((char*)d_ws + 256);

    k_init<<<2048, 256, 0, stream>>>(occ, shift, out + ACC_OFF);
    k_shift<<<SHIFT_BLOCKS, 256, 0, stream>>>(coords, shift);
    k_build<<<(NVOX + 255) / 256, 256, 0, stream>>>(coords, shift, occ);
    // 8 queries/wave, 4 waves/block -> 32 queries/block
    k_query<<<NQ / 32, 256, 0, stream>>>(qpts, feats, occ, shift, out);
}

// Round 4
// 49.371 us; speedup vs baseline: 4.8248x; 1.0333x over previous
//
#include <hip/hip_runtime.h>
#include <limits.h>

#define NBATCH 2
#define DIM 128
#define NVOX 131072
#define NQ 131072
#define OCC_SIZE (NBATCH * DIM * DIM * DIM)   // 4,194,304 ints = 16 MB

// d_out float layout (concatenated reference outputs)
#define QF_OFF  0
#define IDX_OFF (NQ * 128)                // 16,777,216
#define WV_OFF  (IDX_OFF + NQ * 8)        // 17,825,792
#define ACC_OFF (WV_OFF + NQ * 8)         // 18,874,368

#define SHIFT_BLOCKS 64
// d_ws layout: sp[6][64] partial mins at byte 0 (1536 B), occ grid at byte 4096

#define WREDUCE_MIN(mv)                                       \
    _Pragma("unroll")                                         \
    for (int off = 32; off >= 1; off >>= 1)                   \
        mv = min(mv, __shfl_xor(mv, off, 64));

// ---- prep: clear occ/accum; blocks 0..63 also reduce coords -> sp (no atomics)
__global__ __launch_bounds__(256) void k_prep(const int* __restrict__ coords,
                                              int* __restrict__ sp,
                                              int* __restrict__ occ,
                                              float* __restrict__ accum) {
    int tid = blockIdx.x * 256 + threadIdx.x;
    int stride = gridDim.x * 256;
    for (int j = tid; j < NVOX; j += stride) accum[j] = 0.f;
    int4* occ4 = (int4*)occ;
    int4 neg1 = make_int4(-1, -1, -1, -1);
    for (int j = tid; j < OCC_SIZE / 4; j += stride) occ4[j] = neg1;

    if (blockIdx.x < SHIFT_BLOCKS) {
        __shared__ int sm[4][6];
        int i0 = blockIdx.x * 256 + threadIdx.x;
        int sstride = SHIFT_BLOCKS * 256;
        int m0 = INT_MAX, m1 = INT_MAX, m2 = INT_MAX;
        int m3 = INT_MAX, m4 = INT_MAX, m5 = INT_MAX;
        const int4* c4 = (const int4*)coords;
        for (int i = i0; i < NVOX; i += sstride) {
            int4 c = c4[i];
            if (c.x == 0) { m0 = min(m0, c.y); m1 = min(m1, c.z); m2 = min(m2, c.w); }
            else          { m3 = min(m3, c.y); m4 = min(m4, c.z); m5 = min(m5, c.w); }
        }
        WREDUCE_MIN(m0) WREDUCE_MIN(m1) WREDUCE_MIN(m2)
        WREDUCE_MIN(m3) WREDUCE_MIN(m4) WREDUCE_MIN(m5)
        int wave = threadIdx.x >> 6;
        if ((threadIdx.x & 63) == 0) {
            sm[wave][0] = m0; sm[wave][1] = m1; sm[wave][2] = m2;
            sm[wave][3] = m3; sm[wave][4] = m4; sm[wave][5] = m5;
        }
        __syncthreads();
        if (threadIdx.x == 0) {
            #pragma unroll
            for (int c = 0; c < 6; ++c) {
                int v = min(min(sm[0][c], sm[1][c]), min(sm[2][c], sm[3][c]));
                sp[c * SHIFT_BLOCKS + blockIdx.x] = v;   // plain store, no init needed
            }
        }
    }
}

// ---- per-block: reduce the 64 partial mins into sh[6] (wave 0), sync ----
__device__ __forceinline__ void load_shift(const int* __restrict__ sp, int* sh) {
    if (threadIdx.x < 64) {
        int l = threadIdx.x;
        #pragma unroll
        for (int c = 0; c < 6; ++c) {
            int v = sp[c * SHIFT_BLOCKS + l];
            WREDUCE_MIN(v)
            if (l == 0) sh[c] = v;
        }
    }
    __syncthreads();
}

// ---------------- build occupancy: last-write-wins == atomicMax -------------
__global__ __launch_bounds__(256) void k_build(const int* __restrict__ coords,
                                               const int* __restrict__ sp,
                                               int* __restrict__ occ) {
    __shared__ int sh[6];
    load_shift(sp, sh);
    int i = blockIdx.x * 256 + threadIdx.x;      // grid exactly NVOX/256 blocks
    int4 c = ((const int4*)coords)[i];
    int b = c.x;
    int x = c.y - sh[b * 3 + 0];
    int y = c.z - sh[b * 3 + 1];
    int z = c.w - sh[b * 3 + 2];
    atomicMax(&occ[((b * DIM + x) * DIM + y) * DIM + z], i);
}

// -------- main: 8 queries per wave. Scalar phase: lane=(qi,corner k). -------
// -------- Gather phase: ballot-compacted, lane=channel pair.          -------
__global__ __launch_bounds__(256) void k_query(
    const float* __restrict__ qpts, const float* __restrict__ feats,
    const int* __restrict__ occ, const int* __restrict__ sp,
    float* __restrict__ out) {
    __shared__ int sh[6];
    load_shift(sp, sh);

    int lane = threadIdx.x & 63;
    int gwave = blockIdx.x * 4 + (threadIdx.x >> 6);
    int qbase = gwave * 8;                     // 8 queries per wave

    // ---- scalar phase: this lane handles corner k of query qbase+qi ----
    int qi = lane >> 3, k = lane & 7;
    int q = qbase + qi;
    float4 qp = ((const float4*)qpts)[q];
    int qb = (int)qp.x;
    float qx = qp.y - (float)sh[qb * 3 + 0];
    float qy = qp.z - (float)sh[qb * 3 + 1];
    float qz = qp.w - (float)sh[qb * 3 + 2];
    float fx0 = floorf(qx), fy0 = floorf(qy), fz0 = floorf(qz);
    float fx = qx - fx0, fy = qy - fy0, fz = qz - fz0;
    int ox = (k >> 2) & 1, oy = (k >> 1) & 1, oz = k & 1;
    int cx = (int)fx0 + ox, cy = (int)fy0 + oy, cz = (int)fz0 + oz;
    bool inb = ((unsigned)cx < DIM) && ((unsigned)cy < DIM) && ((unsigned)cz < DIM);
    int ccx = min(max(cx, 0), DIM - 1);
    int ccy = min(max(cy, 0), DIM - 1);
    int ccz = min(max(cz, 0), DIM - 1);
    int idx = occ[((qb * DIM + ccx) * DIM + ccy) * DIM + ccz];
    float w = (ox ? fx : 1.f - fx) * (oy ? fy : 1.f - fy) * (oz ? fz : 1.f - fz);
    bool valid = inb && (idx >= 0);
    float wvk = valid ? w : 0.f;

    // coalesced side outputs: q*8+k == qbase*8 + lane
    out[IDX_OFF + (size_t)qbase * 8 + lane] = valid ? (float)idx : -1.f;
    out[WV_OFF  + (size_t)qbase * 8 + lane] = wvk;
    if (valid && wvk != 0.f) atomicAdd(out + ACC_OFF + idx, wvk);

    // per-query wsum: reduce within each 8-lane group; approx reciprocal once
    float wsum = wvk;
    wsum += __shfl_xor(wsum, 1, 64);
    wsum += __shfl_xor(wsum, 2, 64);
    wsum += __shfl_xor(wsum, 4, 64);
    float inv = __builtin_amdgcn_rcpf(fmaxf(wsum, 1e-8f));

    // ---- gather phase: lane = channel pair; only valid corners touched ----
    int sidx = valid ? idx : 0;
    unsigned long long vm = __ballot(wvk != 0.f);
    const float2* f2 = (const float2*)feats;
    float2 acc[8];
#pragma unroll
    for (int g = 0; g < 8; ++g) { acc[g].x = 0.f; acc[g].y = 0.f; }
#pragma unroll
    for (int g = 0; g < 8; ++g) {
        unsigned int sub = (unsigned int)(vm >> (g * 8)) & 0xffu;
        while (sub) {                          // wave-uniform loop
            int j = __ffs(sub) - 1; sub &= sub - 1;
            int src = g * 8 + j;
            float wv_j = __shfl(wvk, src, 64);
            int   idx_j = __shfl(sidx, src, 64);
            float2 fv = f2[(size_t)idx_j * 64 + lane];
            acc[g].x = fmaf(wv_j, fv.x, acc[g].x);
            acc[g].y = fmaf(wv_j, fv.y, acc[g].y);
        }
    }

    // ---- epilogue: 8 coalesced float2 stores ----
    float2* qf = (float2*)(out + QF_OFF);
#pragma unroll
    for (int g = 0; g < 8; ++g) {
        float iv = __shfl(inv, g * 8, 64);
        float2 r;
        r.x = acc[g].x * iv;
        r.y = acc[g].y * iv;
        qf[(size_t)(qbase + g) * 64 + lane] = r;
    }
}

extern "C" void kernel_launch(void* const* d_in, const int* in_sizes, int n_in,
                              void* d_out, int out_size, void* d_ws, size_t ws_size,
                              hipStream_t stream) {
    const int*   coords = (const int*)d_in[0];
    const float* feats  = (const float*)d_in[1];
    const float* qpts   = (const float*)d_in[2];
    float* out = (float*)d_out;

    int* sp  = (int*)d_ws;                       // [6][64] partial mins
    int* occ = (int*)((char*)d_ws + 4096);       // 16 MB grid

    k_prep<<<2048, 256, 0, stream>>>(coords, sp, occ, out + ACC_OFF);
    k_build<<<NVOX / 256, 256, 0, stream>>>(coords, sp, occ);
    k_query<<<NQ / 32, 256, 0, stream>>>(qpts, feats, occ, sp, out);
}

// Round 5
// 46.322 us; speedup vs baseline: 5.1424x; 1.0658x over previous
//
#include <hip/hip_runtime.h>
#include <limits.h>

#define DIM 128
#define NVOX 131072
#define NQ 131072
#define NCELL (2 * DIM * DIM * DIM)        // 4,194,304 cells
#define BITWORDS (NCELL / 64)              // 65,536 x 8B = 512 KB bitmap

// d_out float layout (concatenated reference outputs)
#define QF_OFF  0
#define IDX_OFF (NQ * 128)                 // 16,777,216
#define WV_OFF  (IDX_OFF + NQ * 8)         // 17,825,792
#define ACC_OFF (WV_OFF + NQ * 8)          // 18,874,368

#define SHIFT_BLOCKS 64
// d_ws layout: sp[6][64] @0, bitmap @4096 (512KB), idx grid @528384 (16MB)

typedef float vf2 __attribute__((ext_vector_type(2)));

#define WREDUCE_MIN(mv)                                       \
    _Pragma("unroll")                                         \
    for (int off = 32; off >= 1; off >>= 1)                   \
        mv = min(mv, __shfl_xor(mv, off, 64));

// cell index from UNSHIFTED coords (b in bit 21, x 14, y 7, z 0)
__device__ __forceinline__ int cell_of(int b, int x, int y, int z) {
    return (b << 21) + (x << 14) + (y << 7) + z;
}

// ---- prep: clear bitmap/accum, clear ONLY touched idx cells, coord min ----
__global__ __launch_bounds__(256) void k_prep(const int* __restrict__ coords,
                                              int* __restrict__ sp,
                                              unsigned long long* __restrict__ bitmap,
                                              int* __restrict__ idxg,
                                              float* __restrict__ accum) {
    int tid = blockIdx.x * 256 + threadIdx.x;          // grid = 512 blocks -> 131072
    int4 c = ((const int4*)coords)[tid];
    idxg[cell_of(c.x, c.y, c.z, c.w)] = -1;            // scattered pre-clear
    if (tid < BITWORDS) bitmap[tid] = 0ull;
    accum[tid] = 0.f;

    if (blockIdx.x < SHIFT_BLOCKS) {                   // per-batch component mins
        __shared__ int sm[4][6];
        int i0 = blockIdx.x * 256 + threadIdx.x;
        int sstride = SHIFT_BLOCKS * 256;
        int m0 = INT_MAX, m1 = INT_MAX, m2 = INT_MAX;
        int m3 = INT_MAX, m4 = INT_MAX, m5 = INT_MAX;
        const int4* c4 = (const int4*)coords;
        for (int i = i0; i < NVOX; i += sstride) {
            int4 v = c4[i];
            if (v.x == 0) { m0 = min(m0, v.y); m1 = min(m1, v.z); m2 = min(m2, v.w); }
            else          { m3 = min(m3, v.y); m4 = min(m4, v.z); m5 = min(m5, v.w); }
        }
        WREDUCE_MIN(m0) WREDUCE_MIN(m1) WREDUCE_MIN(m2)
        WREDUCE_MIN(m3) WREDUCE_MIN(m4) WREDUCE_MIN(m5)
        int wave = threadIdx.x >> 6;
        if ((threadIdx.x & 63) == 0) {
            sm[wave][0] = m0; sm[wave][1] = m1; sm[wave][2] = m2;
            sm[wave][3] = m3; sm[wave][4] = m4; sm[wave][5] = m5;
        }
        __syncthreads();
        if (threadIdx.x == 0) {
            #pragma unroll
            for (int k = 0; k < 6; ++k)
                sp[k * SHIFT_BLOCKS + blockIdx.x] =
                    min(min(sm[0][k], sm[1][k]), min(sm[2][k], sm[3][k]));
        }
    }
}

// ---- build: set occupancy bit + max voxel index (last-write-wins == max) ----
__global__ __launch_bounds__(256) void k_build(const int* __restrict__ coords,
                                               unsigned long long* __restrict__ bitmap,
                                               int* __restrict__ idxg) {
    int i = blockIdx.x * 256 + threadIdx.x;            // grid = 512 blocks
    int4 c = ((const int4*)coords)[i];
    int cell = cell_of(c.x, c.y, c.z, c.w);
    atomicOr(&bitmap[cell >> 6], 1ull << (cell & 63));
    atomicMax(&idxg[cell], i);
}

// ---- per-block: reduce the 64 partial mins into sh[6] (wave 0), sync ----
__device__ __forceinline__ void load_shift(const int* __restrict__ sp, int* sh) {
    if (threadIdx.x < 64) {
        int l = threadIdx.x;
        #pragma unroll
        for (int k = 0; k < 6; ++k) {
            int v = sp[k * SHIFT_BLOCKS + l];
            WREDUCE_MIN(v)
            if (l == 0) sh[k] = v;
        }
    }
    __syncthreads();
}

// -------- main: 8 queries per wave. Scalar phase: lane=(qi,corner k). -------
// -------- Probe bitmap (L2-resident) first; idx grid only on set bits. ------
__global__ __launch_bounds__(256) void k_query(
    const float* __restrict__ qpts, const float* __restrict__ feats,
    const unsigned long long* __restrict__ bitmap, const int* __restrict__ idxg,
    const int* __restrict__ sp, float* __restrict__ out) {
    __shared__ int sh[6];
    load_shift(sp, sh);

    int lane = threadIdx.x & 63;
    int gwave = blockIdx.x * 4 + (threadIdx.x >> 6);
    int qbase = gwave * 8;                     // 8 queries per wave

    // ---- scalar phase: this lane handles corner k of query qbase+qi ----
    int qi = lane >> 3, k = lane & 7;
    int q = qbase + qi;
    float4 qp = ((const float4*)qpts)[q];
    int qb = (int)qp.x;
    // fracs are shift-invariant (shift is integer); corners in UNSHIFTED space
    float fx0 = floorf(qp.y), fy0 = floorf(qp.z), fz0 = floorf(qp.w);
    float fx = qp.y - fx0, fy = qp.z - fy0, fz = qp.w - fz0;
    int ox = (k >> 2) & 1, oy = (k >> 1) & 1, oz = k & 1;
    int ux = (int)fx0 + ox, uy = (int)fy0 + oy, uz = (int)fz0 + oz;
    // in-bounds test is in SHIFTED space (reference semantics)
    bool inb = ((unsigned)(ux - sh[qb * 3 + 0]) < DIM) &&
               ((unsigned)(uy - sh[qb * 3 + 1]) < DIM) &&
               ((unsigned)(uz - sh[qb * 3 + 2]) < DIM);
    int cx = min(max(ux, 0), DIM - 1);
    int cy = min(max(uy, 0), DIM - 1);
    int cz = min(max(uz, 0), DIM - 1);
    int cell = cell_of(qb, cx, cy, cz);
    unsigned long long wbits = bitmap[cell >> 6];
    bool occb = ((wbits >> (cell & 63)) & 1ull) != 0ull
                && ((unsigned)ux < DIM) && ((unsigned)uy < DIM) && ((unsigned)uz < DIM);
    bool valid = inb && occb;
    int idx = 0;
    if (valid) idx = idxg[cell];               // ~3% of lanes: tiny fill traffic

    float w = (ox ? fx : 1.f - fx) * (oy ? fy : 1.f - fy) * (oz ? fz : 1.f - fz);
    float wvk = valid ? w : 0.f;

    // coalesced side outputs: q*8+k == qbase*8 + lane (nontemporal: streaming)
    __builtin_nontemporal_store(valid ? (float)idx : -1.f,
                                out + IDX_OFF + (size_t)qbase * 8 + lane);
    __builtin_nontemporal_store(wvk, out + WV_OFF + (size_t)qbase * 8 + lane);
    if (valid && wvk != 0.f) atomicAdd(out + ACC_OFF + idx, wvk);

    // per-query wsum: reduce within each 8-lane group; approx reciprocal
    float wsum = wvk;
    wsum += __shfl_xor(wsum, 1, 64);
    wsum += __shfl_xor(wsum, 2, 64);
    wsum += __shfl_xor(wsum, 4, 64);
    float inv = __builtin_amdgcn_rcpf(fmaxf(wsum, 1e-8f));

    // ---- gather phase: lane = channel pair; only valid corners touched ----
    int sidx = valid ? idx : 0;
    unsigned long long vm = __ballot(wvk != 0.f);
    const vf2* f2 = (const vf2*)feats;
    vf2 acc[8];
#pragma unroll
    for (int g = 0; g < 8; ++g) { acc[g] = (vf2){0.f, 0.f}; }
#pragma unroll
    for (int g = 0; g < 8; ++g) {
        unsigned int sub = (unsigned int)(vm >> (g * 8)) & 0xffu;
        while (sub) {                          // wave-uniform loop
            int j = __ffs(sub) - 1; sub &= sub - 1;
            int src = g * 8 + j;
            float wv_j = __shfl(wvk, src, 64);
            int   idx_j = __shfl(sidx, src, 64);
            vf2 fv = f2[(size_t)idx_j * 64 + lane];
            acc[g].x = fmaf(wv_j, fv.x, acc[g].x);
            acc[g].y = fmaf(wv_j, fv.y, acc[g].y);
        }
    }

    // ---- epilogue: 8 coalesced nontemporal float2 stores ----
    vf2* qf = (vf2*)(out + QF_OFF);
#pragma unroll
    for (int g = 0; g < 8; ++g) {
        float iv = __shfl(inv, g * 8, 64);
        vf2 r;
        r.x = acc[g].x * iv;
        r.y = acc[g].y * iv;
        __builtin_nontemporal_store(r, qf + (size_t)(qbase + g) * 64 + lane);
    }
}

extern "C" void kernel_launch(void* const* d_in, const int* in_sizes, int n_in,
                              void* d_out, int out_size, void* d_ws, size_t ws_size,
                              hipStream_t stream) {
    const int*   coords = (const int*)d_in[0];
    const float* feats  = (const float*)d_in[1];
    const float* qpts   = (const float*)d_in[2];
    float* out = (float*)d_out;

    int* sp = (int*)d_ws;                                          // [6][64]
    unsigned long long* bitmap = (unsigned long long*)((char*)d_ws + 4096);  // 512 KB
    int* idxg = (int*)((char*)d_ws + 4096 + BITWORDS * 8);         // 16 MB

    k_prep<<<NVOX / 256, 256, 0, stream>>>(coords, sp, bitmap, idxg, out + ACC_OFF);
    k_build<<<NVOX / 256, 256, 0, stream>>>(coords, bitmap, idxg);
    k_query<<<NQ / 32, 256, 0, stream>>>(qpts, feats, bitmap, idxg, sp, out);
}

// Round 6
// 44.521 us; speedup vs baseline: 5.3504x; 1.0405x over previous
//
#include <hip/hip_runtime.h>
#include <limits.h>

#define DIM 128
#define NVOX 131072
#define NQ 131072
#define NCELL (2 * DIM * DIM * DIM)        // 4,194,304 cells
#define BITWORDS (NCELL / 64)              // 65,536 x 8B = 512 KB bitmap

// d_out float layout (concatenated reference outputs)
#define QF_OFF  0
#define IDX_OFF (NQ * 128)                 // 16,777,216
#define WV_OFF  (IDX_OFF + NQ * 8)         // 17,825,792
#define ACC_OFF (WV_OFF + NQ * 8)          // 18,874,368

#define SHIFT_BLOCKS 64
// d_ws layout: sp[6][64] @0, bitmap @4096 (512KB), idx grid @528384 (16MB)

typedef float vf2 __attribute__((ext_vector_type(2)));

#define WREDUCE_MIN(mv)                                       \
    _Pragma("unroll")                                         \
    for (int off = 32; off >= 1; off >>= 1)                   \
        mv = min(mv, __shfl_xor(mv, off, 64));

// cell index from UNSHIFTED coords (b in bit 21, x 14, y 7, z 0)
__device__ __forceinline__ int cell_of(int b, int x, int y, int z) {
    return (b << 21) + (x << 14) + (y << 7) + z;
}

// ---- prep: clear bitmap/accum, clear ONLY touched idx cells, coord min ----
__global__ __launch_bounds__(256) void k_prep(const int* __restrict__ coords,
                                              int* __restrict__ sp,
                                              unsigned long long* __restrict__ bitmap,
                                              int* __restrict__ idxg,
                                              float* __restrict__ accum) {
    int tid = blockIdx.x * 256 + threadIdx.x;          // grid = 512 blocks -> 131072
    int4 c = ((const int4*)coords)[tid];
    idxg[cell_of(c.x, c.y, c.z, c.w)] = -1;            // scattered pre-clear
    if (tid < BITWORDS) bitmap[tid] = 0ull;
    accum[tid] = 0.f;

    if (blockIdx.x < SHIFT_BLOCKS) {                   // per-batch component mins
        __shared__ int sm[4][6];
        int i0 = blockIdx.x * 256 + threadIdx.x;
        int sstride = SHIFT_BLOCKS * 256;
        int m0 = INT_MAX, m1 = INT_MAX, m2 = INT_MAX;
        int m3 = INT_MAX, m4 = INT_MAX, m5 = INT_MAX;
        const int4* c4 = (const int4*)coords;
        for (int i = i0; i < NVOX; i += sstride) {
            int4 v = c4[i];
            if (v.x == 0) { m0 = min(m0, v.y); m1 = min(m1, v.z); m2 = min(m2, v.w); }
            else          { m3 = min(m3, v.y); m4 = min(m4, v.z); m5 = min(m5, v.w); }
        }
        WREDUCE_MIN(m0) WREDUCE_MIN(m1) WREDUCE_MIN(m2)
        WREDUCE_MIN(m3) WREDUCE_MIN(m4) WREDUCE_MIN(m5)
        int wave = threadIdx.x >> 6;
        if ((threadIdx.x & 63) == 0) {
            sm[wave][0] = m0; sm[wave][1] = m1; sm[wave][2] = m2;
            sm[wave][3] = m3; sm[wave][4] = m4; sm[wave][5] = m5;
        }
        __syncthreads();
        if (threadIdx.x == 0) {
            #pragma unroll
            for (int k = 0; k < 6; ++k)
                sp[k * SHIFT_BLOCKS + blockIdx.x] =
                    min(min(sm[0][k], sm[1][k]), min(sm[2][k], sm[3][k]));
        }
    }
}

// ---- build: set occupancy bit + max voxel index (last-write-wins == max) ----
__global__ __launch_bounds__(256) void k_build(const int* __restrict__ coords,
                                               unsigned long long* __restrict__ bitmap,
                                               int* __restrict__ idxg) {
    int i = blockIdx.x * 256 + threadIdx.x;            // grid = 512 blocks
    int4 c = ((const int4*)coords)[i];
    int cell = cell_of(c.x, c.y, c.z, c.w);
    atomicOr(&bitmap[cell >> 6], 1ull << (cell & 63));
    atomicMax(&idxg[cell], i);
}

// ---- per-block: reduce the 64 partial mins into sh[6] (wave 0), sync ----
__device__ __forceinline__ void load_shift(const int* __restrict__ sp, int* sh) {
    if (threadIdx.x < 64) {
        int l = threadIdx.x;
        #pragma unroll
        for (int k = 0; k < 6; ++k) {
            int v = sp[k * SHIFT_BLOCKS + l];
            WREDUCE_MIN(v)
            if (l == 0) sh[k] = v;
        }
    }
    __syncthreads();
}

// -------- main: 32 queries per wave in 4 rounds of (qi,corner) lanes. -------
// -------- Phase-split for MLP: addresses -> all loads -> resolve -> gather. -
__global__ __launch_bounds__(256) void k_query(
    const float* __restrict__ qpts, const float* __restrict__ feats,
    const unsigned long long* __restrict__ bitmap, const int* __restrict__ idxg,
    const int* __restrict__ sp, float* __restrict__ out) {
    __shared__ int sh[6];
    load_shift(sp, sh);

    int lane = threadIdx.x & 63;
    int gwave = blockIdx.x * 4 + (threadIdx.x >> 6);
    int qbase = gwave * 32;                    // 32 queries per wave
    int qi = lane >> 3, k = lane & 7;
    const int ox = (k >> 2) & 1, oy = (k >> 1) & 1, oz = k & 1;

    // ---- pass A: all 4 query loads (independent) ----
    float4 qp[4];
#pragma unroll
    for (int r = 0; r < 4; ++r)
        qp[r] = ((const float4*)qpts)[qbase + r * 8 + qi];

    // ---- pass B: compute cells, issue all bitmap loads back-to-back ----
    int cell[4]; bool inb[4]; float w[4];
    unsigned long long wbits[4];
#pragma unroll
    for (int r = 0; r < 4; ++r) {
        int qb = (int)qp[r].x;
        float fx0 = floorf(qp[r].y), fy0 = floorf(qp[r].z), fz0 = floorf(qp[r].w);
        float fx = qp[r].y - fx0, fy = qp[r].z - fy0, fz = qp[r].w - fz0;
        int ux = (int)fx0 + ox, uy = (int)fy0 + oy, uz = (int)fz0 + oz;
        bool sb = ((unsigned)(ux - sh[qb * 3 + 0]) < DIM) &&
                  ((unsigned)(uy - sh[qb * 3 + 1]) < DIM) &&
                  ((unsigned)(uz - sh[qb * 3 + 2]) < DIM);
        inb[r] = sb && ((unsigned)ux < DIM) && ((unsigned)uy < DIM) && ((unsigned)uz < DIM);
        int cx = min(max(ux, 0), DIM - 1);
        int cy = min(max(uy, 0), DIM - 1);
        int cz = min(max(uz, 0), DIM - 1);
        cell[r] = cell_of(qb, cx, cy, cz);
        w[r] = (ox ? fx : 1.f - fx) * (oy ? fy : 1.f - fy) * (oz ? fz : 1.f - fz);
    }
#pragma unroll
    for (int r = 0; r < 4; ++r) wbits[r] = bitmap[cell[r] >> 6];

    // ---- pass C: resolve validity, idx loads, side outputs, ballots ----
    float wv[4]; int sidx[4]; float inv[4]; unsigned long long vm[4];
#pragma unroll
    for (int r = 0; r < 4; ++r) {
        bool valid = inb[r] && (((wbits[r] >> (cell[r] & 63)) & 1ull) != 0ull);
        int idx = 0;
        if (valid) idx = idxg[cell[r]];
        float wvk = valid ? w[r] : 0.f;
        wv[r] = wvk;
        sidx[r] = valid ? idx : 0;
        __builtin_nontemporal_store(valid ? (float)idx : -1.f,
            out + IDX_OFF + (size_t)qbase * 8 + r * 64 + lane);
        __builtin_nontemporal_store(wvk,
            out + WV_OFF + (size_t)qbase * 8 + r * 64 + lane);
        if (valid && wvk != 0.f) atomicAdd(out + ACC_OFF + idx, wvk);
        float wsum = wvk;
        wsum += __shfl_xor(wsum, 1, 64);
        wsum += __shfl_xor(wsum, 2, 64);
        wsum += __shfl_xor(wsum, 4, 64);
        inv[r] = __builtin_amdgcn_rcpf(fmaxf(wsum, 1e-8f));
        vm[r] = __ballot(wvk != 0.f);
    }

    // ---- pass D: 32 gather+store bodies, consecutive queries independent ----
    const vf2* f2 = (const vf2*)feats;
    vf2* qf = (vf2*)(out + QF_OFF);
#pragma unroll
    for (int g = 0; g < 32; ++g) {
        const int r = g >> 3, gq = g & 7;
        unsigned int sub = (unsigned int)(vm[r] >> (gq * 8)) & 0xffu;
        vf2 acc = (vf2){0.f, 0.f};
        while (sub) {                          // wave-uniform loop, ~3% taken
            int j = __ffs(sub) - 1; sub &= sub - 1;
            int src = gq * 8 + j;
            float wv_j = __shfl(wv[r], src, 64);
            int   idx_j = __shfl(sidx[r], src, 64);
            vf2 fv = f2[(size_t)idx_j * 64 + lane];
            acc.x = fmaf(wv_j, fv.x, acc.x);
            acc.y = fmaf(wv_j, fv.y, acc.y);
        }
        float iv = __shfl(inv[r], gq * 8, 64);
        vf2 res;
        res.x = acc.x * iv;
        res.y = acc.y * iv;
        __builtin_nontemporal_store(res, qf + (size_t)(qbase + g) * 64 + lane);
    }
}

extern "C" void kernel_launch(void* const* d_in, const int* in_sizes, int n_in,
                              void* d_out, int out_size, void* d_ws, size_t ws_size,
                              hipStream_t stream) {
    const int*   coords = (const int*)d_in[0];
    const float* feats  = (const float*)d_in[1];
    const float* qpts   = (const float*)d_in[2];
    float* out = (float*)d_out;

    int* sp = (int*)d_ws;                                          // [6][64]
    unsigned long long* bitmap = (unsigned long long*)((char*)d_ws + 4096);  // 512 KB
    int* idxg = (int*)((char*)d_ws + 4096 + BITWORDS * 8);         // 16 MB

    k_prep<<<NVOX / 256, 256, 0, stream>>>(coords, sp, bitmap, idxg, out + ACC_OFF);
    k_build<<<NVOX / 256, 256, 0, stream>>>(coords, bitmap, idxg);
    // 32 queries/wave, 4 waves/block -> 128 queries/block
    k_query<<<NQ / 128, 256, 0, stream>>>(qpts, feats, bitmap, idxg, sp, out);
}